// Round 4
// baseline (1857.808 us; speedup 1.0000x reference)
//
#include <hip/hip_runtime.h>
#include <hip/hip_bf16.h>
#include <stdint.h>

// Problem constants
#define Bb 16
#define Ss 2048
#define Dd 1024
#define Hh 1024
#define Rr 16
#define Mm 32768   // B*S

typedef __attribute__((ext_vector_type(4))) float f32x4;
typedef __attribute__((ext_vector_type(8))) short bf16x8;
typedef __attribute__((ext_vector_type(2))) _Float16 h2;

// RNE fp32 -> bf16 bits
__device__ __forceinline__ unsigned short f2bf(float f) {
    union { float f; uint32_t u; } c; c.f = f;
    uint32_t u = c.u + 0x7fffu + ((c.u >> 16) & 1u);
    return (unsigned short)(u >> 16);
}
__device__ __forceinline__ float bfbits2f(uint32_t bits) {
    union { uint32_t u; float f; } c; c.u = bits << 16; return c.f;
}
__device__ __forceinline__ h2 u2h(unsigned int x) {
    union { unsigned int u; h2 h; } c; c.u = x; return c.h;
}
__device__ __forceinline__ h2 mkh2(float a, float b) {
    h2 r; r.x = (_Float16)a; r.y = (_Float16)b; return r;
}

// v_dot2_f32_f16: c + a.x*b.x + a.y*b.y (f32 accumulate)
__device__ __forceinline__ float DOT2(h2 a, h2 b, float c) {
#if __has_builtin(__builtin_amdgcn_fdot2)
    return __builtin_amdgcn_fdot2(a, b, c, false);
#else
    return fmaf((float)a.x, (float)b.x, fmaf((float)a.y, (float)b.y, c));
#endif
}

// DPP cross-lane moves (VALU pipe, NOT the DS pipe).
// row_ror:8 within each 16-row == lane^8 exchange ((i+8) mod 16 == i^8)
__device__ __forceinline__ float dpp_xor8(float x) {
    return __int_as_float(__builtin_amdgcn_mov_dpp(
        __float_as_int(x), 0x128, 0xF, 0xF, false));
}
// quad_perm(1,0,3,2) == lane^1 exchange
__device__ __forceinline__ float dpp_xor1(float x) {
    return __int_as_float(__builtin_amdgcn_mov_dpp(
        __float_as_int(x), 0xB1, 0xF, 0xF, false));
}

// async global->LDS, 16B per lane. LDS dest = uniform base + lane*16.
__device__ __forceinline__ void gld16(const void* gsrc, void* ldst) {
    __builtin_amdgcn_global_load_lds(
        (const __attribute__((address_space(1))) unsigned int*)gsrc,
        (__attribute__((address_space(3))) unsigned int*)ldst, 16, 0, 0);
}

// Raw workgroup barrier WITHOUT the vmcnt(0) drain __syncthreads carries.
// lgkmcnt(0) makes LDS writes visible across waves; outstanding global
// (prefetch) loads stay in flight.
// imm 0xC07F = vmcnt(63) expcnt(7) lgkmcnt(0)  [gfx9 encoding]
__device__ __forceinline__ void softbar() {
    __asm volatile("" ::: "memory");
    __builtin_amdgcn_s_waitcnt(0xC07F);
    __builtin_amdgcn_s_barrier();
    __asm volatile("" ::: "memory");
}

// ---------------------------------------------------------------------------
// Kernel 1: convert x, Wa, Wu to bf16 (flat, 4 elems/thread)
// ---------------------------------------------------------------------------
__global__ __launch_bounds__(256) void k_convert(
    const float* __restrict__ x, const float* __restrict__ Wa,
    const float* __restrict__ Wu,
    unsigned short* __restrict__ xb, unsigned short* __restrict__ Wab,
    unsigned short* __restrict__ Wub)
{
    long e = ((long)blockIdx.x * 256 + threadIdx.x) * 4;
    const long nx = (long)Mm * Dd;        // 33,554,432
    const long nw = (long)Hh * Dd;        // 1,048,576
    const float* src; unsigned short* dst; long o;
    if (e < nx)            { src = x;  dst = xb;  o = e; }
    else if (e < nx + nw)  { src = Wa; dst = Wab; o = e - nx; }
    else                   { src = Wu; dst = Wub; o = e - nx - nw; }
    float4 f = *(const float4*)(src + o);
    ushort4 r;
    r.x = f2bf(f.x); r.y = f2bf(f.y); r.z = f2bf(f.z); r.w = f2bf(f.w);
    *(ushort4*)(dst + o) = r;
}

// ---------------------------------------------------------------------------
// Kernel 2: C[M,1024] = Xb @ W^T (+bias, optional sigmoid), bf16 MFMA.
// ---------------------------------------------------------------------------
__global__ __launch_bounds__(256) void k_gemm(
    const unsigned short* __restrict__ Xb,   // [M, D] bf16 bits
    const unsigned short* __restrict__ Wab,  // [H, D]
    const unsigned short* __restrict__ Wub,  // [H, D]
    const float* __restrict__ ba, const float* __restrict__ bu,
    unsigned short* __restrict__ outA, unsigned short* __restrict__ outU)
{
    __shared__ short At[128 * 32];
    __shared__ short Bt[128 * 32];

    const int tid  = threadIdx.x;
    const int lane = tid & 63;
    const int wave = tid >> 6;
    const int bm = blockIdx.x;
    const int bn = blockIdx.y;
    const int region = bn >> 3;            // 0: a, 1: u_in
    const int nbase = (bn & 7) * 128;

    const short* Ag = (const short*)Xb;
    const short* Bg = (const short*)(region ? Wub : Wab);
    const float* bias = region ? bu : ba;
    unsigned short* outp = region ? outU : outA;

    const int wm = wave & 1, wn = wave >> 1;
    const int srow = lane >> 2, sseg = lane & 3;   // staging: 4 lanes/row
    const int mrow = lane & 15, kb = lane >> 4;    // fragment lane mapping

    f32x4 acc[4][4] = {};

    for (int kt = 0; kt < 32; ++kt) {
        __syncthreads();
        const int k0 = kt * 32;
        #pragma unroll
        for (int p = 0; p < 2; ++p) {
            const int row = p * 64 + wave * 16 + srow;
            const short* ga = Ag + (long)(bm * 128 + row) * Dd + k0 + sseg * 8;
            gld16((const void*)ga, (void*)&At[p * 2048 + wave * 512]);
            const short* gb = Bg + (long)(nbase + row) * Dd + k0 + sseg * 8;
            gld16((const void*)gb, (void*)&Bt[p * 2048 + wave * 512]);
        }
        __syncthreads();

        bf16x8 af[4], bq[4];
        #pragma unroll
        for (int i = 0; i < 4; ++i) {
            af[i] = *(const bf16x8*)&At[(wm * 64 + i * 16 + mrow) * 32 + kb * 8];
            bq[i] = *(const bf16x8*)&Bt[(wn * 64 + i * 16 + mrow) * 32 + kb * 8];
        }
        #pragma unroll
        for (int i = 0; i < 4; ++i)
            #pragma unroll
            for (int j = 0; j < 4; ++j)
                acc[i][j] = __builtin_amdgcn_mfma_f32_16x16x32_bf16(
                    af[i], bq[j], acc[i][j], 0, 0, 0);
    }

    // Epilogue: C/D layout col=lane&15, row=(lane>>4)*4+reg (m89-verified)
    const int col = lane & 15, rq = lane >> 4;
    #pragma unroll
    for (int j = 0; j < 4; ++j) {
        const int n = nbase + wn * 64 + j * 16 + col;
        const float bv = bias[n];
        #pragma unroll
        for (int i = 0; i < 4; ++i) {
            const int mb = bm * 128 + wm * 64 + i * 16 + rq * 4;
            #pragma unroll
            for (int r = 0; r < 4; ++r) {
                float vv = acc[i][j][r] + bv;
                if (region == 0) vv = 1.0f / (1.0f + __expf(-vv));
                outp[(long)(mb + r) * Hh + n] = f2bf(vv);
            }
        }
    }
}

// ---------------------------------------------------------------------------
// Kernel 3: g[M,16] = x @ Wg^T + bg (fp32, tiny N)
// ---------------------------------------------------------------------------
__global__ __launch_bounds__(256) void k_g(
    const float* __restrict__ x, const float* __restrict__ Wg,
    const float* __restrict__ bg, float* __restrict__ g)
{
    const int tid = threadIdx.x;
    const int r = tid & 15, ml = tid >> 4;
    const long m = (long)blockIdx.x * 16 + ml;
    const float4* xr = (const float4*)(x + m * Dd);
    const float4* wr = (const float4*)(Wg + (long)r * Dd);
    float acc = 0.0f;
    #pragma unroll 4
    for (int k = 0; k < Dd / 4; ++k) {
        float4 a = xr[k], b = wr[k];
        acc = fmaf(a.x, b.x, acc); acc = fmaf(a.y, b.y, acc);
        acc = fmaf(a.z, b.z, acc); acc = fmaf(a.w, b.w, acc);
    }
    g[m * Rr + r] = acc + bg[r];
}

// ---------------------------------------------------------------------------
// Kernel 4: sequential scan. 16 blocks x 512 threads (8 waves, 2 h/thread).
// The scan is DS-PIPE THROUGHPUT bound (round-2 model: ~72 return-bus
// cyc/wave/step x 16 waves ~= measured 1357 cyc/step). This version cuts the
// per-CU DS budget ~2.5x:
//  - 8 waves instead of 16: per-lane-invariant broadcasts (qh read, sh
//    write) cost half per CU.
//  - Phase A half-split: lane (o=lane>>3, p=lane&7) reads ONE 16-h window
//    (2x b128) and computes TWO partials r=p and r=p+8 -> per-CU A-read
//    traffic halves. Cross-o reduction: xor8 via mov_dpp row_ror:8 (VALU!),
//    then xor16/xor32 shfl. After hops every lane holds wavepart[r=lane&15].
//  - Phase C half-split: thread reads ONE b128 of qh (8 q's, its side),
//    computes side-partials for its own 2 h's AND its xor1-partner's 2 h's,
//    then one quad_perm DPP exchange (VALU) + add completes lr.
//  - sh write: one packed b32 (2 adjacent fp16) per thread.
// All LDS patterns <=2-way bank aliasing (free). fp32 state in registers;
// fp16 shadows for communication (proven in round 2, absmax unchanged).
// ---------------------------------------------------------------------------
__global__ __launch_bounds__(512) void k_scan(
    const unsigned short* __restrict__ a,    // [B,S,H] bf16
    const unsigned short* __restrict__ uin,  // [B,S,H] bf16
    const float* __restrict__ g,    // [B,S,R]
    const float* __restrict__ u,    // [H,R]
    const float* __restrict__ v,    // [H,R]
    float* __restrict__ out)        // [B,H]
{
    __shared__ __align__(16) _Float16 sh[Hh];       // fp16 state shadow, 2 KB
    __shared__ __align__(16) _Float16 cacc[16 * 8]; // [r][w], 256 B
    __shared__ __align__(32) _Float16 qh[16];       // fp16 q, 32 B

    const int tid  = threadIdx.x;       // 0..511
    const int lane = tid & 63;
    const int wave = tid >> 6;          // 0..7
    const int oA   = lane >> 3;         // 16-h block within wave's 128
    const int pA   = lane & 7;          // r-pair id (r = pA and pA+8)
    const int side = tid & 1;           // q-half owned in phase C
    const int b = blockIdx.x;

    const int h0 = 2 * tid;             // owned states
    // phase-A consts: v[hW + 2k .. +1][pA] and [pA+8], fp16 pairs
    const int hW = wave * 128 + oA * 16;
    h2 vrA[8], vrB[8];
    #pragma unroll
    for (int k = 0; k < 8; ++k) {
        vrA[k] = mkh2(v[(hW + 2 * k) * Rr + pA],
                      v[(hW + 2 * k + 1) * Rr + pA]);
        vrB[k] = mkh2(v[(hW + 2 * k) * Rr + pA + 8],
                      v[(hW + 2 * k + 1) * Rr + pA + 8]);
    }
    // phase-C consts: U rows for own h's (h0,h0+1) and xor1-partner's h's,
    // restricted to this thread's q-side (8 r's), as fp16 pairs.
    const int hp0 = 2 * (tid ^ 1);
    h2 ur00[4], ur01[4], urP0[4], urP1[4];
    #pragma unroll
    for (int k = 0; k < 4; ++k) {
        const int r0 = 8 * side + 2 * k;
        ur00[k] = mkh2(u[(h0)     * Rr + r0], u[(h0)     * Rr + r0 + 1]);
        ur01[k] = mkh2(u[(h0 + 1) * Rr + r0], u[(h0 + 1) * Rr + r0 + 1]);
        urP0[k] = mkh2(u[(hp0)     * Rr + r0], u[(hp0)     * Rr + r0 + 1]);
        urP1[k] = mkh2(u[(hp0 + 1) * Rr + r0], u[(hp0 + 1) * Rr + r0 + 1]);
    }

    // streams: one b32 per step covers both owned h's (2 bf16)
    const uint32_t* apu = (const uint32_t*)(a   + (long)b * Ss * Hh) + tid;
    const uint32_t* upu = (const uint32_t*)(uin + (long)b * Ss * Hh) + tid;
    const float*    gp  = g + (long)b * Ss * Rr + tid;   // tid<16 only

    float s0 = 0.0f, s1 = 0.0f;
    uint32_t pa[4], pu[4]; float pg[4];
    #pragma unroll
    for (int t = 0; t < 4; ++t) { pa[t] = apu[t * 512]; pu[t] = upu[t * 512]; }
    apu += 4 * 512; upu += 4 * 512;
    if (tid < 16) {
        #pragma unroll
        for (int t = 0; t < 4; ++t) pg[t] = gp[t * Rr];
        gp += 4 * Rr;
    }

    ((uint32_t*)sh)[tid] = 0u;
    __syncthreads();

    const _Float16* spA = &sh[hW];
    const _Float16* qpC = &qh[8 * side];
    const h2 one2 = mkh2(1.0f, 1.0f);

#define STEP(R, PF) do {                                                    \
    /* A: two partials (r=pA, pA+8) over the 16-h window, 16x dot2 */       \
    uint4 sA = *(const uint4*)(spA);                                        \
    uint4 sB = *(const uint4*)(spA + 8);                                    \
    float lo, hi;                                                           \
    lo = DOT2(u2h(sA.x), vrA[0], 0.0f);                                     \
    lo = DOT2(u2h(sA.y), vrA[1], lo);                                       \
    lo = DOT2(u2h(sA.z), vrA[2], lo);                                       \
    lo = DOT2(u2h(sA.w), vrA[3], lo);                                       \
    lo = DOT2(u2h(sB.x), vrA[4], lo);                                       \
    lo = DOT2(u2h(sB.y), vrA[5], lo);                                       \
    lo = DOT2(u2h(sB.z), vrA[6], lo);                                       \
    lo = DOT2(u2h(sB.w), vrA[7], lo);                                       \
    hi = DOT2(u2h(sA.x), vrB[0], 0.0f);                                     \
    hi = DOT2(u2h(sA.y), vrB[1], hi);                                       \
    hi = DOT2(u2h(sA.z), vrB[2], hi);                                       \
    hi = DOT2(u2h(sA.w), vrB[3], hi);                                       \
    hi = DOT2(u2h(sB.x), vrB[4], hi);                                       \
    hi = DOT2(u2h(sB.y), vrB[5], hi);                                       \
    hi = DOT2(u2h(sB.z), vrB[6], hi);                                       \
    hi = DOT2(u2h(sB.w), vrB[7], hi);                                       \
    /* reduce over o: xor8 (DPP, VALU) with lo/hi halving, then xor16/32 */ \
    {                                                                       \
        float tlo = dpp_xor8(lo), thi = dpp_xor8(hi);                       \
        float v1 = (lane & 8) ? (hi + thi) : (lo + tlo);                    \
        v1 += __shfl_xor(v1, 16);                                           \
        v1 += __shfl_xor(v1, 32);                                           \
        if (lane < 16) cacc[lane * 8 + wave] = (_Float16)v1;                \
    }                                                                       \
    /* capture streams, then issue prefetch before the barrier */           \
    float a0 = bfbits2f(pa[R] & 0xFFFFu), a1 = bfbits2f(pa[R] >> 16);       \
    float u0 = bfbits2f(pu[R] & 0xFFFFu), u1 = bfbits2f(pu[R] >> 16);       \
    if (PF) {                                                               \
        pa[R] = *apu; apu += 512;                                           \
        pu[R] = *upu; upu += 512;                                           \
    }                                                                       \
    softbar(); /* bar1: cacc visible */                                     \
    /* B: q[r] = g_t[r] * sum_w cacc[r][w]  (wave 0, lanes<16) */           \
    if (tid < 16) {                                                         \
        uint4 c = *(const uint4*)&cacc[tid * 8];                            \
        float ssum;                                                         \
        ssum = DOT2(u2h(c.x), one2, 0.0f);                                  \
        ssum = DOT2(u2h(c.y), one2, ssum);                                  \
        ssum = DOT2(u2h(c.z), one2, ssum);                                  \
        ssum = DOT2(u2h(c.w), one2, ssum);                                  \
        qh[tid] = (_Float16)(pg[R] * ssum);                                 \
        if (PF) { pg[R] = *gp; gp += Rr; }                                  \
    }                                                                       \
    softbar(); /* bar2: qh visible */                                       \
    /* C: one b128 of qh (own side); side-partials for own 2 h's and the */ \
    /* xor1-partner's 2 h's; DPP xor1 exchange completes lr. */             \
    uint4 q4 = *(const uint4*)qpC;                                          \
    h2 q0 = u2h(q4.x), q1 = u2h(q4.y), q2 = u2h(q4.z), q3 = u2h(q4.w);     \
    float pO0 = DOT2(q0, ur00[0],                                           \
                DOT2(q1, ur00[1], DOT2(q2, ur00[2], DOT2(q3, ur00[3], 0.0f))));\
    float pO1 = DOT2(q0, ur01[0],                                           \
                DOT2(q1, ur01[1], DOT2(q2, ur01[2], DOT2(q3, ur01[3], 0.0f))));\
    float pP0 = DOT2(q0, urP0[0],                                           \
                DOT2(q1, urP0[1], DOT2(q2, urP0[2], DOT2(q3, urP0[3], 0.0f))));\
    float pP1 = DOT2(q0, urP1[0],                                           \
                DOT2(q1, urP1[1], DOT2(q2, urP1[2], DOT2(q3, urP1[3], 0.0f))));\
    float lr0 = pO0 + dpp_xor1(pP0);                                        \
    float lr1 = pO1 + dpp_xor1(pP1);                                        \
    s0 = fmaf(a0, s0, u0 + lr0);                                            \
    s1 = fmaf(a1, s1, u1 + lr1);                                            \
    {                                                                       \
        union { _Float16 h[2]; uint32_t u32; } pk;                          \
        pk.h[0] = (_Float16)s0; pk.h[1] = (_Float16)s1;                     \
        ((uint32_t*)sh)[tid] = pk.u32;                                      \
    }                                                                       \
    softbar(); /* bar3: state visible */                                    \
} while (0)

    for (int t4 = 0; t4 < Ss / 4 - 1; ++t4) {
        STEP(0, 1); STEP(1, 1); STEP(2, 1); STEP(3, 1);
    }
    STEP(0, 0); STEP(1, 0); STEP(2, 0); STEP(3, 0);
#undef STEP

    *(float2*)(out + (long)b * Hh + h0) = make_float2(s0, s1);
}

// ---------------------------------------------------------------------------
extern "C" void kernel_launch(void* const* d_in, const int* in_sizes, int n_in,
                              void* d_out, int out_size, void* d_ws, size_t ws_size,
                              hipStream_t stream)
{
    const float* x  = (const float*)d_in[0];
    const float* Wa = (const float*)d_in[1];
    const float* ba = (const float*)d_in[2];
    const float* Wg = (const float*)d_in[3];
    const float* bg = (const float*)d_in[4];
    const float* Wu = (const float*)d_in[5];
    const float* bu = (const float*)d_in[6];
    const float* u  = (const float*)d_in[7];
    const float* v  = (const float*)d_in[8];
    float* out = (float*)d_out;

    char* ws = (char*)d_ws;
    unsigned short* xb   = (unsigned short*)(ws);                // 67,108,864 B
    unsigned short* Wab  = (unsigned short*)(ws + 67108864);     //  2,097,152 B
    unsigned short* Wub  = (unsigned short*)(ws + 69206016);     //  2,097,152 B
    unsigned short* abuf = (unsigned short*)(ws + 71303168);     // 67,108,864 B (bf16)
    unsigned short* ubuf = (unsigned short*)(ws + 138412032);    // 67,108,864 B (bf16)
    float*          gbuf = (float*)(ws + 205520896);             //  2,097,152 B

    hipLaunchKernelGGL(k_convert, dim3(34816), dim3(256), 0, stream,
                       x, Wa, Wu, xb, Wab, Wub);
    hipLaunchKernelGGL(k_gemm, dim3(256, 16), dim3(256), 0, stream,
                       xb, Wab, Wub, ba, bu, abuf, ubuf);
    hipLaunchKernelGGL(k_g, dim3(2048), dim3(256), 0, stream,
                       x, Wg, bg, gbuf);
    hipLaunchKernelGGL(k_scan, dim3(Bb), dim3(512), 0, stream,
                       abuf, ubuf, gbuf, u, v, out);
}

// Round 5
// 1590.793 us; speedup vs baseline: 1.1679x; 1.1679x over previous
//
#include <hip/hip_runtime.h>
#include <hip/hip_bf16.h>
#include <stdint.h>

// Problem constants
#define Bb 16
#define Ss 2048
#define Dd 1024
#define Hh 1024
#define Rr 16
#define Mm 32768   // B*S

typedef __attribute__((ext_vector_type(4))) float f32x4;
typedef __attribute__((ext_vector_type(8))) short bf16x8;
typedef __attribute__((ext_vector_type(2))) _Float16 h2;

// RNE fp32 -> bf16 bits
__device__ __forceinline__ unsigned short f2bf(float f) {
    union { float f; uint32_t u; } c; c.f = f;
    uint32_t u = c.u + 0x7fffu + ((c.u >> 16) & 1u);
    return (unsigned short)(u >> 16);
}
__device__ __forceinline__ float bfbits2f(uint32_t bits) {
    union { uint32_t u; float f; } c; c.u = bits << 16; return c.f;
}
__device__ __forceinline__ h2 u2h(unsigned int x) {
    union { unsigned int u; h2 h; } c; c.u = x; return c.h;
}
__device__ __forceinline__ h2 mkh2(float a, float b) {
    h2 r; r.x = (_Float16)a; r.y = (_Float16)b; return r;
}
__device__ __forceinline__ uint32_t h2u(h2 x) {
    union { h2 h; uint32_t u; } c; c.h = x; return c.u;
}

// v_dot2_f32_f16: c + a.x*b.x + a.y*b.y (f32 accumulate)
__device__ __forceinline__ float DOT2(h2 a, h2 b, float c) {
#if __has_builtin(__builtin_amdgcn_fdot2)
    return __builtin_amdgcn_fdot2(a, b, c, false);
#else
    return fmaf((float)a.x, (float)b.x, fmaf((float)a.y, (float)b.y, c));
#endif
}

// DPP cross-lane move (VALU pipe). row_ror:8 within each 16-row == lane^8-ish
// exchange: lane l receives from lane (l&~15)|(((l&15)+8)&15).
__device__ __forceinline__ float dpp_xor8(float x) {
    return __int_as_float(__builtin_amdgcn_mov_dpp(
        __float_as_int(x), 0x128, 0xF, 0xF, false));
}

// async global->LDS, 16B per lane. LDS dest = uniform base + lane*16.
__device__ __forceinline__ void gld16(const void* gsrc, void* ldst) {
    __builtin_amdgcn_global_load_lds(
        (const __attribute__((address_space(1))) unsigned int*)gsrc,
        (__attribute__((address_space(3))) unsigned int*)ldst, 16, 0, 0);
}

// Raw workgroup barrier WITHOUT the vmcnt(0) drain __syncthreads carries.
// lgkmcnt(0) makes LDS writes visible across waves; outstanding global
// (prefetch) loads stay in flight.
// imm 0xC07F = vmcnt(63) expcnt(7) lgkmcnt(0)  [gfx9 encoding]
__device__ __forceinline__ void softbar() {
    __asm volatile("" ::: "memory");
    __builtin_amdgcn_s_waitcnt(0xC07F);
    __builtin_amdgcn_s_barrier();
    __asm volatile("" ::: "memory");
}

// ---------------------------------------------------------------------------
// Kernel 1: convert x, Wa, Wu to bf16 (flat, 4 elems/thread)
// ---------------------------------------------------------------------------
__global__ __launch_bounds__(256) void k_convert(
    const float* __restrict__ x, const float* __restrict__ Wa,
    const float* __restrict__ Wu,
    unsigned short* __restrict__ xb, unsigned short* __restrict__ Wab,
    unsigned short* __restrict__ Wub)
{
    long e = ((long)blockIdx.x * 256 + threadIdx.x) * 4;
    const long nx = (long)Mm * Dd;        // 33,554,432
    const long nw = (long)Hh * Dd;        // 1,048,576
    const float* src; unsigned short* dst; long o;
    if (e < nx)            { src = x;  dst = xb;  o = e; }
    else if (e < nx + nw)  { src = Wa; dst = Wab; o = e - nx; }
    else                   { src = Wu; dst = Wub; o = e - nx - nw; }
    float4 f = *(const float4*)(src + o);
    ushort4 r;
    r.x = f2bf(f.x); r.y = f2bf(f.y); r.z = f2bf(f.z); r.w = f2bf(f.w);
    *(ushort4*)(dst + o) = r;
}

// ---------------------------------------------------------------------------
// Kernel 2: C[M,1024] = Xb @ W^T (+bias, optional sigmoid), bf16 MFMA.
// ---------------------------------------------------------------------------
__global__ __launch_bounds__(256) void k_gemm(
    const unsigned short* __restrict__ Xb,   // [M, D] bf16 bits
    const unsigned short* __restrict__ Wab,  // [H, D]
    const unsigned short* __restrict__ Wub,  // [H, D]
    const float* __restrict__ ba, const float* __restrict__ bu,
    unsigned short* __restrict__ outA, unsigned short* __restrict__ outU)
{
    __shared__ short At[128 * 32];
    __shared__ short Bt[128 * 32];

    const int tid  = threadIdx.x;
    const int lane = tid & 63;
    const int wave = tid >> 6;
    const int bm = blockIdx.x;
    const int bn = blockIdx.y;
    const int region = bn >> 3;            // 0: a, 1: u_in
    const int nbase = (bn & 7) * 128;

    const short* Ag = (const short*)Xb;
    const short* Bg = (const short*)(region ? Wub : Wab);
    const float* bias = region ? bu : ba;
    unsigned short* outp = region ? outU : outA;

    const int wm = wave & 1, wn = wave >> 1;
    const int srow = lane >> 2, sseg = lane & 3;   // staging: 4 lanes/row
    const int mrow = lane & 15, kb = lane >> 4;    // fragment lane mapping

    f32x4 acc[4][4] = {};

    for (int kt = 0; kt < 32; ++kt) {
        __syncthreads();
        const int k0 = kt * 32;
        #pragma unroll
        for (int p = 0; p < 2; ++p) {
            const int row = p * 64 + wave * 16 + srow;
            const short* ga = Ag + (long)(bm * 128 + row) * Dd + k0 + sseg * 8;
            gld16((const void*)ga, (void*)&At[p * 2048 + wave * 512]);
            const short* gb = Bg + (long)(nbase + row) * Dd + k0 + sseg * 8;
            gld16((const void*)gb, (void*)&Bt[p * 2048 + wave * 512]);
        }
        __syncthreads();

        bf16x8 af[4], bq[4];
        #pragma unroll
        for (int i = 0; i < 4; ++i) {
            af[i] = *(const bf16x8*)&At[(wm * 64 + i * 16 + mrow) * 32 + kb * 8];
            bq[i] = *(const bf16x8*)&Bt[(wn * 64 + i * 16 + mrow) * 32 + kb * 8];
        }
        #pragma unroll
        for (int i = 0; i < 4; ++i)
            #pragma unroll
            for (int j = 0; j < 4; ++j)
                acc[i][j] = __builtin_amdgcn_mfma_f32_16x16x32_bf16(
                    af[i], bq[j], acc[i][j], 0, 0, 0);
    }

    // Epilogue: C/D layout col=lane&15, row=(lane>>4)*4+reg (m89-verified)
    const int col = lane & 15, rq = lane >> 4;
    #pragma unroll
    for (int j = 0; j < 4; ++j) {
        const int n = nbase + wn * 64 + j * 16 + col;
        const float bv = bias[n];
        #pragma unroll
        for (int i = 0; i < 4; ++i) {
            const int mb = bm * 128 + wm * 64 + i * 16 + rq * 4;
            #pragma unroll
            for (int r = 0; r < 4; ++r) {
                float vv = acc[i][j][r] + bv;
                if (region == 0) vv = 1.0f / (1.0f + __expf(-vv));
                outp[(long)(mb + r) * Hh + n] = f2bf(vv);
            }
        }
    }
}

// ---------------------------------------------------------------------------
// Kernel 3: g[M,16] = x @ Wg^T + bg (fp32, tiny N)
// ---------------------------------------------------------------------------
__global__ __launch_bounds__(256) void k_g(
    const float* __restrict__ x, const float* __restrict__ Wg,
    const float* __restrict__ bg, float* __restrict__ g)
{
    const int tid = threadIdx.x;
    const int r = tid & 15, ml = tid >> 4;
    const long m = (long)blockIdx.x * 16 + ml;
    const float4* xr = (const float4*)(x + m * Dd);
    const float4* wr = (const float4*)(Wg + (long)r * Dd);
    float acc = 0.0f;
    #pragma unroll 4
    for (int k = 0; k < Dd / 4; ++k) {
        float4 a = xr[k], b = wr[k];
        acc = fmaf(a.x, b.x, acc); acc = fmaf(a.y, b.y, acc);
        acc = fmaf(a.z, b.z, acc); acc = fmaf(a.w, b.w, acc);
    }
    g[m * Rr + r] = acc + bg[r];
}

// ---------------------------------------------------------------------------
// Kernel 3b: K[16,16] = V^T U  (K[r][c] = sum_h v[h][r]*u[h][c])
// One block, 256 threads, one entry each. ~µs.
// ---------------------------------------------------------------------------
__global__ __launch_bounds__(256) void k_K(
    const float* __restrict__ u, const float* __restrict__ v,
    float* __restrict__ Kbuf)
{
    const int r = threadIdx.x >> 4;
    const int c = threadIdx.x & 15;
    float acc = 0.0f;
    for (int h = 0; h < Hh; ++h)
        acc = fmaf(v[h * Rr + r], u[h * Rr + c], acc);
    Kbuf[r * 16 + c] = acc;
}

// ---------------------------------------------------------------------------
// Kernel 4: sequential scan, ONE barrier per step. 16 blocks x 512 threads.
//
// Rounds 0-4 showed the scan pinned at ~1390 cyc/step regardless of DS
// traffic (3-phase = 3 barrier round-trips each carrying ~120cyc LDS
// latency + dep chains). This version collapses the sequential chain to
// 16 dims via K = V^T U (precomputed):
//   y_{t+1} = w_t + K q_t,   q_t = g_t (.) y_t,   w_t = V^T tmp_t,
//   tmp_t = a_t (.) s_{t-1} + u_t,   s_t = tmp_t + U q_t.
// Per body(t): [window reads of tmp-shadow issued immediately after the
// previous barrier] -> q_t (dpp pair + 8 readlane -> SGPRs) -> lr (16 dot2)
// -> s_t -> tmp_{t+1} -> shadow write (buffer (t+1)&1) -> w_t wave-partials
// (16 dot2 + xor8 dpp + xor16/32 shfl) -> cacc write (buffer t&1) ->
// SOFTBAR -> cacc row read (1 b128) -> y_{t+1} = w + K q (12 dot2).
// Shadow and cacc are double-buffered by step parity => single barrier is
// race-free (writes always target the opposite buffer from concurrent
// readers; the barrier separates same-buffer write->read).
// All LDS patterns <=2-way bank aliasing. State fp32 in regs; fp16 only on
// communication paths (proven rounds 2/4).
// ---------------------------------------------------------------------------
__global__ __launch_bounds__(512) void k_scan(
    const unsigned short* __restrict__ a,    // [B,S,H] bf16
    const unsigned short* __restrict__ uin,  // [B,S,H] bf16
    const float* __restrict__ g,    // [B,S,R]
    const float* __restrict__ u,    // [H,R]
    const float* __restrict__ v,    // [H,R]
    const float* __restrict__ Kbuf, // [16,16] = V^T U
    float* __restrict__ out)        // [B,H]
{
    __shared__ __align__(16) h2 shad[2][512];          // tmp~ shadow, 2x2KB
    __shared__ __align__(16) _Float16 cacc[2][16][8];  // w partials [r][w]

    const int tid  = threadIdx.x;       // 0..511
    const int lane = tid & 63;
    const int wave = tid >> 6;          // 0..7
    const int oA   = lane >> 3;         // 16-h window within wave's 128
    const int pA   = lane & 7;          // r-pair id for phase-A dots
    const int ra   = lane & 15;         // r owned for y/q/cacc-row
    const int b    = blockIdx.x;
    const int h0   = 2 * tid;           // owned states

    // phase-A V coefficients over the window [hW, hW+16)
    const int hW = wave * 128 + oA * 16;
    h2 vrA[8], vrB[8];
    #pragma unroll
    for (int k = 0; k < 8; ++k) {
        vrA[k] = mkh2(v[(hW + 2*k) * Rr + pA],
                      v[(hW + 2*k + 1) * Rr + pA]);
        vrB[k] = mkh2(v[(hW + 2*k) * Rr + pA + 8],
                      v[(hW + 2*k + 1) * Rr + pA + 8]);
    }
    // U rows for own 2 h's, paired (j, j+8) to match q packing; K row ra.
    h2 ur0[8], ur1[8], kr[8];
    #pragma unroll
    for (int j = 0; j < 8; ++j) {
        ur0[j] = mkh2(u[h0 * Rr + j],        u[h0 * Rr + j + 8]);
        ur1[j] = mkh2(u[(h0 + 1) * Rr + j],  u[(h0 + 1) * Rr + j + 8]);
        kr[j]  = mkh2(Kbuf[ra * 16 + j],     Kbuf[ra * 16 + j + 8]);
    }

    const uint32_t* apu = (const uint32_t*)(a   + (long)b * Ss * Hh) + tid;
    const uint32_t* upu = (const uint32_t*)(uin + (long)b * Ss * Hh) + tid;
    const float*    gp  = g + (long)b * Ss * Rr + ra;    // all lanes

    float s0 = 0.0f, s1 = 0.0f, y = 0.0f;

    // rings: body(t) consumes a/u slot (t+1)&3 (= row t, feeds tmp_{t+1})
    //        and g slot t&3 (= row t-1, feeds q_t).
    uint32_t pa_[4], pu_[4]; float pg_[4];
    pa_[2] = apu[1*512]; pa_[3] = apu[2*512]; pa_[0] = apu[3*512]; pa_[1] = apu[4*512];
    pu_[2] = upu[1*512]; pu_[3] = upu[2*512]; pu_[0] = upu[3*512]; pu_[1] = upu[4*512];
    uint32_t u0r = upu[0];
    apu += 5 * 512; upu += 5 * 512;
    pg_[1] = gp[0]; pg_[2] = gp[Rr]; pg_[3] = gp[2*Rr]; pg_[0] = gp[3*Rr];
    gp += 4 * Rr;

    // tmp~_1 = a_1*s_0 + u_1 = u_1  (s_0 = 0)
    float tA = bfbits2f(u0r & 0xFFFFu);
    float tB = bfbits2f(u0r >> 16);
    shad[1][tid] = mkh2(tA, tB);
    __syncthreads();

    const h2 one2 = mkh2(1.0f, 1.0f);

#define BODY(RG, RA, PAR, PF) do {                                          \
    /* early: window reads (data visible since previous barrier) */         \
    uint4 w0 = *(const uint4*)&shad[PAR][wave * 64 + oA * 8];               \
    uint4 w1 = *(const uint4*)&shad[PAR][wave * 64 + oA * 8 + 4];           \
    /* q_t: distributed y -> pair-pack -> 8 readlanes (SGPR broadcast) */   \
    float q = pg_[RG] * y;                                                  \
    float qo = dpp_xor8(q);                                                 \
    uint32_t qpk = h2u(mkh2(q, qo));                                        \
    uint32_t qv[8];                                                         \
    qv[0] = (uint32_t)__builtin_amdgcn_readlane((int)qpk, 0);               \
    qv[1] = (uint32_t)__builtin_amdgcn_readlane((int)qpk, 1);               \
    qv[2] = (uint32_t)__builtin_amdgcn_readlane((int)qpk, 2);               \
    qv[3] = (uint32_t)__builtin_amdgcn_readlane((int)qpk, 3);               \
    qv[4] = (uint32_t)__builtin_amdgcn_readlane((int)qpk, 4);               \
    qv[5] = (uint32_t)__builtin_amdgcn_readlane((int)qpk, 5);               \
    qv[6] = (uint32_t)__builtin_amdgcn_readlane((int)qpk, 6);               \
    qv[7] = (uint32_t)__builtin_amdgcn_readlane((int)qpk, 7);               \
    /* s_t = tmp_t + U q_t */                                               \
    float lr0, lr1;                                                         \
    lr0 = DOT2(u2h(qv[0]), ur0[0], 0.0f);                                   \
    lr0 = DOT2(u2h(qv[1]), ur0[1], lr0); lr0 = DOT2(u2h(qv[2]), ur0[2], lr0);\
    lr0 = DOT2(u2h(qv[3]), ur0[3], lr0); lr0 = DOT2(u2h(qv[4]), ur0[4], lr0);\
    lr0 = DOT2(u2h(qv[5]), ur0[5], lr0); lr0 = DOT2(u2h(qv[6]), ur0[6], lr0);\
    lr0 = DOT2(u2h(qv[7]), ur0[7], lr0);                                    \
    lr1 = DOT2(u2h(qv[0]), ur1[0], 0.0f);                                   \
    lr1 = DOT2(u2h(qv[1]), ur1[1], lr1); lr1 = DOT2(u2h(qv[2]), ur1[2], lr1);\
    lr1 = DOT2(u2h(qv[3]), ur1[3], lr1); lr1 = DOT2(u2h(qv[4]), ur1[4], lr1);\
    lr1 = DOT2(u2h(qv[5]), ur1[5], lr1); lr1 = DOT2(u2h(qv[6]), ur1[6], lr1);\
    lr1 = DOT2(u2h(qv[7]), ur1[7], lr1);                                    \
    s0 = tA + lr0; s1 = tB + lr1;                                           \
    /* tmp_{t+1}, shadow write (opposite buffer) */                         \
    float na0 = bfbits2f(pa_[RA] & 0xFFFFu), na1 = bfbits2f(pa_[RA] >> 16); \
    float nu0 = bfbits2f(pu_[RA] & 0xFFFFu), nu1 = bfbits2f(pu_[RA] >> 16); \
    tA = fmaf(na0, s0, nu0); tB = fmaf(na1, s1, nu1);                       \
    shad[PAR ^ 1][tid] = mkh2(tA, tB);                                      \
    if (PF) { pa_[RA] = *apu; apu += 512; pu_[RA] = *upu; upu += 512;       \
              pg_[RG] = *gp; gp += Rr; }                                    \
    /* w_t wave-partials from window of tmp_t */                            \
    float lo, hi;                                                           \
    lo = DOT2(u2h(w0.x), vrA[0], 0.0f); lo = DOT2(u2h(w0.y), vrA[1], lo);   \
    lo = DOT2(u2h(w0.z), vrA[2], lo);   lo = DOT2(u2h(w0.w), vrA[3], lo);   \
    lo = DOT2(u2h(w1.x), vrA[4], lo);   lo = DOT2(u2h(w1.y), vrA[5], lo);   \
    lo = DOT2(u2h(w1.z), vrA[6], lo);   lo = DOT2(u2h(w1.w), vrA[7], lo);   \
    hi = DOT2(u2h(w0.x), vrB[0], 0.0f); hi = DOT2(u2h(w0.y), vrB[1], hi);   \
    hi = DOT2(u2h(w0.z), vrB[2], hi);   hi = DOT2(u2h(w0.w), vrB[3], hi);   \
    hi = DOT2(u2h(w1.x), vrB[4], hi);   hi = DOT2(u2h(w1.y), vrB[5], hi);   \
    hi = DOT2(u2h(w1.z), vrB[6], hi);   hi = DOT2(u2h(w1.w), vrB[7], hi);   \
    {                                                                       \
        float tlo = dpp_xor8(lo), thi = dpp_xor8(hi);                       \
        float v1 = (lane & 8) ? (hi + thi) : (lo + tlo);                    \
        v1 += __shfl_xor(v1, 16);                                           \
        v1 += __shfl_xor(v1, 32);                                           \
        if (lane < 16) cacc[PAR][lane][wave] = (_Float16)v1;                \
    }                                                                       \
    softbar(); /* the single barrier */                                     \
    /* y_{t+1} = w_t + K q_t */                                             \
    uint4 c4 = *(const uint4*)&cacc[PAR][ra][0];                            \
    float wf;                                                               \
    wf = DOT2(u2h(c4.x), one2, 0.0f); wf = DOT2(u2h(c4.y), one2, wf);       \
    wf = DOT2(u2h(c4.z), one2, wf);   wf = DOT2(u2h(c4.w), one2, wf);       \
    float ky;                                                               \
    ky = DOT2(u2h(qv[0]), kr[0], 0.0f);                                     \
    ky = DOT2(u2h(qv[1]), kr[1], ky); ky = DOT2(u2h(qv[2]), kr[2], ky);     \
    ky = DOT2(u2h(qv[3]), kr[3], ky); ky = DOT2(u2h(qv[4]), kr[4], ky);     \
    ky = DOT2(u2h(qv[5]), kr[5], ky); ky = DOT2(u2h(qv[6]), kr[6], ky);     \
    ky = DOT2(u2h(qv[7]), kr[7], ky);                                       \
    y = wf + ky;                                                            \
} while (0)

    // bodies t = 1..2048; (RG,RA,PAR) = (t&3, (t+1)&3, t&1)
    for (int t4 = 0; t4 < 511; ++t4) {
        BODY(1, 2, 1, 1); BODY(2, 3, 0, 1); BODY(3, 0, 1, 1); BODY(0, 1, 0, 1);
    }
    BODY(1, 2, 1, 0); BODY(2, 3, 0, 0); BODY(3, 0, 1, 0); BODY(0, 1, 0, 0);
#undef BODY

    *(float2*)(out + (long)b * Hh + h0) = make_float2(s0, s1);
}

// ---------------------------------------------------------------------------
extern "C" void kernel_launch(void* const* d_in, const int* in_sizes, int n_in,
                              void* d_out, int out_size, void* d_ws, size_t ws_size,
                              hipStream_t stream)
{
    const float* x  = (const float*)d_in[0];
    const float* Wa = (const float*)d_in[1];
    const float* ba = (const float*)d_in[2];
    const float* Wg = (const float*)d_in[3];
    const float* bg = (const float*)d_in[4];
    const float* Wu = (const float*)d_in[5];
    const float* bu = (const float*)d_in[6];
    const float* u  = (const float*)d_in[7];
    const float* v  = (const float*)d_in[8];
    float* out = (float*)d_out;

    char* ws = (char*)d_ws;
    unsigned short* xb   = (unsigned short*)(ws);                // 67,108,864 B
    unsigned short* Wab  = (unsigned short*)(ws + 67108864);     //  2,097,152 B
    unsigned short* Wub  = (unsigned short*)(ws + 69206016);     //  2,097,152 B
    unsigned short* abuf = (unsigned short*)(ws + 71303168);     // 67,108,864 B (bf16)
    unsigned short* ubuf = (unsigned short*)(ws + 138412032);    // 67,108,864 B (bf16)
    float*          gbuf = (float*)(ws + 205520896);             //  2,097,152 B
    // Kbuf aliases the xb region: k_K runs AFTER k_gemm has consumed xb.
    float*          Kbuf = (float*)(ws);                         //  1,024 B

    hipLaunchKernelGGL(k_convert, dim3(34816), dim3(256), 0, stream,
                       x, Wa, Wu, xb, Wab, Wub);
    hipLaunchKernelGGL(k_gemm, dim3(256, 16), dim3(256), 0, stream,
                       xb, Wab, Wub, ba, bu, abuf, ubuf);
    hipLaunchKernelGGL(k_K, dim3(1), dim3(256), 0, stream, u, v, Kbuf);
    hipLaunchKernelGGL(k_g, dim3(2048), dim3(256), 0, stream,
                       x, Wg, bg, gbuf);
    hipLaunchKernelGGL(k_scan, dim3(Bb), dim3(512), 0, stream,
                       abuf, ubuf, gbuf, u, v, Kbuf, out);
}

// Round 7
// 1558.665 us; speedup vs baseline: 1.1919x; 1.0206x over previous
//
#include <hip/hip_runtime.h>
#include <hip/hip_bf16.h>
#include <stdint.h>

// Problem constants
#define Bb 16
#define Ss 2048
#define Dd 1024
#define Hh 1024
#define Rr 16
#define Mm 32768   // B*S

typedef __attribute__((ext_vector_type(4))) float f32x4;
typedef __attribute__((ext_vector_type(8))) short bf16x8;
typedef __attribute__((ext_vector_type(2))) _Float16 h2;

// RNE fp32 -> bf16 bits
__device__ __forceinline__ unsigned short f2bf(float f) {
    union { float f; uint32_t u; } c; c.f = f;
    uint32_t u = c.u + 0x7fffu + ((c.u >> 16) & 1u);
    return (unsigned short)(u >> 16);
}
__device__ __forceinline__ float bfbits2f(uint32_t bits) {
    union { uint32_t u; float f; } c; c.u = bits << 16; return c.f;
}
__device__ __forceinline__ h2 u2h(unsigned int x) {
    union { unsigned int u; h2 h; } c; c.u = x; return c.h;
}
__device__ __forceinline__ h2 mkh2(float a, float b) {
    h2 r; r.x = (_Float16)a; r.y = (_Float16)b; return r;
}
__device__ __forceinline__ uint32_t h2u(h2 x) {
    union { h2 h; uint32_t u; } c; c.h = x; return c.u;
}

// Force AS1 (global) loads for stream prefetches: guarantees global_load
// (vmcnt-only). If these were flat_load they'd count toward lgkmcnt and the
// softbar's lgkmcnt(0) would drain HBM prefetches at every barrier.
__device__ __forceinline__ uint32_t gload_u32(const uint32_t* p) {
    return *(const __attribute__((address_space(1))) uint32_t*)(uintptr_t)p;
}
__device__ __forceinline__ float gload_f32(const float* p) {
    return *(const __attribute__((address_space(1))) float*)(uintptr_t)p;
}

// v_dot2_f32_f16: c + a.x*b.x + a.y*b.y (f32 accumulate)
__device__ __forceinline__ float DOT2(h2 a, h2 b, float c) {
#if __has_builtin(__builtin_amdgcn_fdot2)
    return __builtin_amdgcn_fdot2(a, b, c, false);
#else
    return fmaf((float)a.x, (float)b.x, fmaf((float)a.y, (float)b.y, c));
#endif
}

// DPP cross-lane move (VALU pipe). row_ror:8 within each 16-row == lane^8
__device__ __forceinline__ float dpp_xor8(float x) {
    return __int_as_float(__builtin_amdgcn_mov_dpp(
        __float_as_int(x), 0x128, 0xF, 0xF, false));
}

// async global->LDS, 16B per lane. LDS dest = uniform base + lane*16.
__device__ __forceinline__ void gld16(const void* gsrc, void* ldst) {
    __builtin_amdgcn_global_load_lds(
        (const __attribute__((address_space(1))) unsigned int*)gsrc,
        (__attribute__((address_space(3))) unsigned int*)ldst, 16, 0, 0);
}

// Raw workgroup barrier WITHOUT the vmcnt(0) drain __syncthreads carries.
// imm 0xC07F = vmcnt(63) expcnt(7) lgkmcnt(0)  [gfx9 encoding]
__device__ __forceinline__ void softbar() {
    __asm volatile("" ::: "memory");
    __builtin_amdgcn_s_waitcnt(0xC07F);
    __builtin_amdgcn_s_barrier();
    __asm volatile("" ::: "memory");
}

// ---------------------------------------------------------------------------
// Kernel 1: convert x, Wa, Wu to bf16 (flat, 4 elems/thread)
// ---------------------------------------------------------------------------
__global__ __launch_bounds__(256) void k_convert(
    const float* __restrict__ x, const float* __restrict__ Wa,
    const float* __restrict__ Wu,
    unsigned short* __restrict__ xb, unsigned short* __restrict__ Wab,
    unsigned short* __restrict__ Wub)
{
    long e = ((long)blockIdx.x * 256 + threadIdx.x) * 4;
    const long nx = (long)Mm * Dd;        // 33,554,432
    const long nw = (long)Hh * Dd;        // 1,048,576
    const float* src; unsigned short* dst; long o;
    if (e < nx)            { src = x;  dst = xb;  o = e; }
    else if (e < nx + nw)  { src = Wa; dst = Wab; o = e - nx; }
    else                   { src = Wu; dst = Wub; o = e - nx - nw; }
    float4 f = *(const float4*)(src + o);
    ushort4 r;
    r.x = f2bf(f.x); r.y = f2bf(f.y); r.z = f2bf(f.z); r.w = f2bf(f.w);
    *(ushort4*)(dst + o) = r;
}

// ---------------------------------------------------------------------------
// Kernel 2: C[M,1024] = Xb @ W^T (+bias, optional sigmoid), bf16 MFMA.
// T3 minimum 2-phase: double-buffered LDS, stage(next) issued BEFORE
// compute(cur), ONE __syncthreads per K-step (was 2). Staged loads fly
// during ds_read+MFMA; barrier drains vmcnt for the next buffer.
// ---------------------------------------------------------------------------
__global__ __launch_bounds__(256) void k_gemm(
    const unsigned short* __restrict__ Xb,   // [M, D] bf16 bits
    const unsigned short* __restrict__ Wab,  // [H, D]
    const unsigned short* __restrict__ Wub,  // [H, D]
    const float* __restrict__ ba, const float* __restrict__ bu,
    unsigned short* __restrict__ outA, unsigned short* __restrict__ outU)
{
    __shared__ short At[2][128 * 32];
    __shared__ short Bt[2][128 * 32];

    const int tid  = threadIdx.x;
    const int lane = tid & 63;
    const int wave = tid >> 6;
    const int bm = blockIdx.x;
    const int bn = blockIdx.y;
    const int region = bn >> 3;            // 0: a, 1: u_in
    const int nbase = (bn & 7) * 128;

    const short* Ag = (const short*)Xb;
    const short* Bg = (const short*)(region ? Wub : Wab);
    const float* bias = region ? bu : ba;
    unsigned short* outp = region ? outU : outA;

    const int wm = wave & 1, wn = wave >> 1;
    const int srow = lane >> 2, sseg = lane & 3;   // staging: 4 lanes/row
    const int mrow = lane & 15, kb = lane >> 4;    // fragment lane mapping

    f32x4 acc[4][4] = {};

#define STAGE(BUF, KT) do {                                                  \
    const int k0_ = (KT) * 32;                                               \
    _Pragma("unroll")                                                        \
    for (int p = 0; p < 2; ++p) {                                            \
        const int row_ = p * 64 + wave * 16 + srow;                          \
        const short* ga_ = Ag + (long)(bm * 128 + row_) * Dd + k0_ + sseg*8; \
        gld16((const void*)ga_, (void*)&At[BUF][p * 2048 + wave * 512]);     \
        const short* gb_ = Bg + (long)(nbase + row_) * Dd + k0_ + sseg*8;    \
        gld16((const void*)gb_, (void*)&Bt[BUF][p * 2048 + wave * 512]);     \
    }                                                                        \
} while (0)

    STAGE(0, 0);
    __syncthreads();   // vmcnt(0)+lgkmcnt(0)+barrier: buf0 ready

    int cur = 0;
    for (int kt = 0; kt < 32; ++kt) {
        if (kt < 31) STAGE(cur ^ 1, kt + 1);   // issue next tile first

        bf16x8 af[4], bq[4];
        #pragma unroll
        for (int i = 0; i < 4; ++i) {
            af[i] = *(const bf16x8*)&At[cur][(wm*64 + i*16 + mrow)*32 + kb*8];
            bq[i] = *(const bf16x8*)&Bt[cur][(wn*64 + i*16 + mrow)*32 + kb*8];
        }
        #pragma unroll
        for (int i = 0; i < 4; ++i)
            #pragma unroll
            for (int j = 0; j < 4; ++j)
                acc[i][j] = __builtin_amdgcn_mfma_f32_16x16x32_bf16(
                    af[i], bq[j], acc[i][j], 0, 0, 0);

        __syncthreads();   // staged loads done; all reads of buf[cur] done
        cur ^= 1;
    }
#undef STAGE

    // Epilogue: C/D layout col=lane&15, row=(lane>>4)*4+reg (m89-verified)
    const int col = lane & 15, rq = lane >> 4;
    #pragma unroll
    for (int j = 0; j < 4; ++j) {
        const int n = nbase + wn * 64 + j * 16 + col;
        const float bv = bias[n];
        #pragma unroll
        for (int i = 0; i < 4; ++i) {
            const int mb = bm * 128 + wm * 64 + i * 16 + rq * 4;
            #pragma unroll
            for (int r = 0; r < 4; ++r) {
                float vv = acc[i][j][r] + bv;
                if (region == 0) vv = 1.0f / (1.0f + __expf(-vv));
                outp[(long)(mb + r) * Hh + n] = f2bf(vv);
            }
        }
    }
}

// ---------------------------------------------------------------------------
// Kernel 3: g[M,16] = x @ Wg^T + bg (fp32, tiny N)
// ---------------------------------------------------------------------------
__global__ __launch_bounds__(256) void k_g(
    const float* __restrict__ x, const float* __restrict__ Wg,
    const float* __restrict__ bg, float* __restrict__ g)
{
    const int tid = threadIdx.x;
    const int r = tid & 15, ml = tid >> 4;
    const long m = (long)blockIdx.x * 16 + ml;
    const float4* xr = (const float4*)(x + m * Dd);
    const float4* wr = (const float4*)(Wg + (long)r * Dd);
    float acc = 0.0f;
    #pragma unroll 4
    for (int k = 0; k < Dd / 4; ++k) {
        float4 a = xr[k], b = wr[k];
        acc = fmaf(a.x, b.x, acc); acc = fmaf(a.y, b.y, acc);
        acc = fmaf(a.z, b.z, acc); acc = fmaf(a.w, b.w, acc);
    }
    g[m * Rr + r] = acc + bg[r];
}

// ---------------------------------------------------------------------------
// Kernel 3b: K[16,16] = V^T U  (K[r][c] = sum_h v[h][r]*u[h][c])
// ---------------------------------------------------------------------------
__global__ __launch_bounds__(256) void k_K(
    const float* __restrict__ u, const float* __restrict__ v,
    float* __restrict__ Kbuf)
{
    const int r = threadIdx.x >> 4;
    const int c = threadIdx.x & 15;
    float acc = 0.0f;
    for (int h = 0; h < Hh; ++h)
        acc = fmaf(v[h * Rr + r], u[h * Rr + c], acc);
    Kbuf[r * 16 + c] = acc;
}

// ---------------------------------------------------------------------------
// Kernel 4: sequential scan, SKEWED single-barrier pipeline.
// 16 blocks x 512 threads (8 waves, 2 h/thread).
//
// Algebra (round-5, verified): with w_t = V^T tmp_t, kq_t = K q_t:
//   y_t = w_{t-1} + kq_{t-1};  q_t = g_t.y_t;  s_t = tmp_t + U q_t;
//   tmp_{t+1} = a_{t+1}.s_t + u_{t+1}.
// SKEW: body t consumes {w_{t-1}, kq_{t-1}} published at bar(t-1) and
// publishes {w_t partials (from window of tmp_t, shadow-visible since
// bar(t-1)), kq_t}. tmp_{t+1} depends on w_{t-1} (TWO barriers back), so
// the post-barrier LDS-read latency overlaps the whole body instead of
// sitting on the write-side squeeze. Round-5's per-lane ky (8 dot2 x 512
// lanes) replaced by wave-0-published kq (16 lanes x 8 dot2).
// cacc rows padded to 24 halves: 16B-aligned b128 (48B stride), <=2-way
// banks. Stream prefetches forced to AS1 (vmcnt-only) so softbar's
// lgkmcnt(0) never drains them.
// ---------------------------------------------------------------------------
__global__ __launch_bounds__(512) void k_scan(
    const unsigned short* __restrict__ a,    // [B,S,H] bf16
    const unsigned short* __restrict__ uin,  // [B,S,H] bf16
    const float* __restrict__ g,    // [B,S,R]
    const float* __restrict__ u,    // [H,R]
    const float* __restrict__ v,    // [H,R]
    const float* __restrict__ Kbuf, // [16,16] = V^T U
    float* __restrict__ out)        // [B,H]
{
    __shared__ __align__(16) h2 shad[2][512];            // tmp shadow
    __shared__ __align__(16) _Float16 cacc[2][16][24];   // [r][0..7]=w partials, [8]=kq

    const int tid  = threadIdx.x;       // 0..511
    const int lane = tid & 63;
    const int wave = tid >> 6;          // 0..7
    const int oA   = lane >> 3;         // 16-h window within wave's 128
    const int pA   = lane & 7;          // r-pair id for window dots
    const int ra   = lane & 15;         // r owned for y/q/cacc-row
    const int b    = blockIdx.x;
    const int h0   = 2 * tid;           // owned states

    // window V coefficients over [hW, hW+16)
    const int hW = wave * 128 + oA * 16;
    h2 vrA[8], vrB[8];
    #pragma unroll
    for (int k = 0; k < 8; ++k) {
        vrA[k] = mkh2(v[(hW + 2*k) * Rr + pA],
                      v[(hW + 2*k + 1) * Rr + pA]);
        vrB[k] = mkh2(v[(hW + 2*k) * Rr + pA + 8],
                      v[(hW + 2*k + 1) * Rr + pA + 8]);
    }
    // U rows for own 2 h's, paired (j, j+8) to match q packing; K row ra.
    h2 ur0[8], ur1[8], kr[8];
    #pragma unroll
    for (int j = 0; j < 8; ++j) {
        ur0[j] = mkh2(u[h0 * Rr + j],        u[h0 * Rr + j + 8]);
        ur1[j] = mkh2(u[(h0 + 1) * Rr + j],  u[(h0 + 1) * Rr + j + 8]);
        kr[j]  = mkh2(Kbuf[ra * 16 + j],     Kbuf[ra * 16 + j + 8]);
    }

    const uint32_t* apu = (const uint32_t*)(a   + (long)b * Ss * Hh) + tid;
    const uint32_t* upu = (const uint32_t*)(uin + (long)b * Ss * Hh) + tid;
    const float*    gp  = g + (long)b * Ss * Rr + ra;    // all lanes

    // rings: body t consumes a/u idx t+1 (slot (t+1)&3) and g idx t (slot t&3)
    uint32_t pa_[4], pu_[4]; float pg_[4];
    pa_[1] = apu[1*512]; pa_[2] = apu[2*512]; pa_[3] = apu[3*512]; pa_[0] = apu[4*512];
    pu_[1] = upu[1*512]; pu_[2] = upu[2*512]; pu_[3] = upu[3*512]; pu_[0] = upu[4*512];
    uint32_t u0r = upu[0];
    apu += 5 * 512; upu += 5 * 512;
    pg_[0] = gp[0]; pg_[1] = gp[Rr]; pg_[2] = gp[2*Rr]; pg_[3] = gp[3*Rr];
    gp += 4 * Rr;

    // init: tmp_0 = u_0 (s_{-1}=0); body 0 reads shad[0], cacc[1] (zeros -> y_0=0)
    float tA = bfbits2f(u0r & 0xFFFFu);
    float tB = bfbits2f(u0r >> 16);
    shad[0][tid] = mkh2(tA, tB);
    {
        uint32_t* cz = (uint32_t*)&cacc[0][0][0];
        if (tid < 384) cz[tid] = 0u;     // zero both cacc buffers (768 halves)
    }
    __syncthreads();

    float s0f = 0.0f, s1f = 0.0f;
    const h2 one2 = mkh2(1.0f, 1.0f);

#define BODY(RG, RA, PAR, PF) do {                                          \
    /* reads published at bar(t-1) */                                       \
    uint4 c4 = *(const uint4*)&cacc[(PAR)^1][ra][0];                        \
    uint32_t ck = *(const uint32_t*)&cacc[(PAR)^1][ra][8];                  \
    uint4 w0 = *(const uint4*)&shad[PAR][wave * 64 + oA * 8];               \
    uint4 w1 = *(const uint4*)&shad[PAR][wave * 64 + oA * 8 + 4];           \
    /* y_t = w_{t-1} + kq_{t-1} */                                          \
    float wfa = DOT2(u2h(c4.x), one2, 0.0f);                                \
    float wfb = DOT2(u2h(c4.y), one2, 0.0f);                                \
    wfa = DOT2(u2h(c4.z), one2, wfa);                                       \
    wfb = DOT2(u2h(c4.w), one2, wfb);                                       \
    float y = (wfa + wfb) + (float)(u2h(ck).x);                             \
    /* q_t: distributed -> pair-pack -> 8 readlanes */                      \
    float q = pg_[RG] * y;                                                  \
    float qo = dpp_xor8(q);                                                 \
    uint32_t qpk = h2u(mkh2(q, qo));                                        \
    uint32_t qv0 = (uint32_t)__builtin_amdgcn_readlane((int)qpk, 0);        \
    uint32_t qv1 = (uint32_t)__builtin_amdgcn_readlane((int)qpk, 1);        \
    uint32_t qv2 = (uint32_t)__builtin_amdgcn_readlane((int)qpk, 2);        \
    uint32_t qv3 = (uint32_t)__builtin_amdgcn_readlane((int)qpk, 3);        \
    uint32_t qv4 = (uint32_t)__builtin_amdgcn_readlane((int)qpk, 4);        \
    uint32_t qv5 = (uint32_t)__builtin_amdgcn_readlane((int)qpk, 5);        \
    uint32_t qv6 = (uint32_t)__builtin_amdgcn_readlane((int)qpk, 6);        \
    uint32_t qv7 = (uint32_t)__builtin_amdgcn_readlane((int)qpk, 7);        \
    /* s_t = tmp_t + U q_t (two 4-chains per h) */                          \
    float l0a = DOT2(u2h(qv0), ur0[0], 0.0f);                               \
    float l0b = DOT2(u2h(qv4), ur0[4], 0.0f);                               \
    l0a = DOT2(u2h(qv1), ur0[1], l0a); l0b = DOT2(u2h(qv5), ur0[5], l0b);   \
    l0a = DOT2(u2h(qv2), ur0[2], l0a); l0b = DOT2(u2h(qv6), ur0[6], l0b);   \
    l0a = DOT2(u2h(qv3), ur0[3], l0a); l0b = DOT2(u2h(qv7), ur0[7], l0b);   \
    float l1a = DOT2(u2h(qv0), ur1[0], 0.0f);                               \
    float l1b = DOT2(u2h(qv4), ur1[4], 0.0f);                               \
    l1a = DOT2(u2h(qv1), ur1[1], l1a); l1b = DOT2(u2h(qv5), ur1[5], l1b);   \
    l1a = DOT2(u2h(qv2), ur1[2], l1a); l1b = DOT2(u2h(qv6), ur1[6], l1b);   \
    l1a = DOT2(u2h(qv3), ur1[3], l1a); l1b = DOT2(u2h(qv7), ur1[7], l1b);   \
    s0f = tA + (l0a + l0b);                                                 \
    s1f = tB + (l1a + l1b);                                                 \
    /* tmp_{t+1} = a_{t+1}.s_t + u_{t+1}, shadow write (opposite buffer) */ \
    float na0 = bfbits2f(pa_[RA] & 0xFFFFu), na1 = bfbits2f(pa_[RA] >> 16); \
    float nu0 = bfbits2f(pu_[RA] & 0xFFFFu), nu1 = bfbits2f(pu_[RA] >> 16); \
    tA = fmaf(na0, s0f, nu0); tB = fmaf(na1, s1f, nu1);                     \
    shad[(PAR) ^ 1][tid] = mkh2(tA, tB);                                    \
    if (PF) {                                                               \
        pa_[RA] = gload_u32(apu); apu += 512;                               \
        pu_[RA] = gload_u32(upu); upu += 512;                               \
        pg_[RG] = gload_f32(gp);  gp  += Rr;                                \
    }                                                                       \
    /* w_t partials from window(tmp_t) for r=pA, pA+8 */                    \
    float lo, hi;                                                           \
    lo = DOT2(u2h(w0.x), vrA[0], 0.0f); lo = DOT2(u2h(w0.y), vrA[1], lo);   \
    lo = DOT2(u2h(w0.z), vrA[2], lo);   lo = DOT2(u2h(w0.w), vrA[3], lo);   \
    lo = DOT2(u2h(w1.x), vrA[4], lo);   lo = DOT2(u2h(w1.y), vrA[5], lo);   \
    lo = DOT2(u2h(w1.z), vrA[6], lo);   lo = DOT2(u2h(w1.w), vrA[7], lo);   \
    hi = DOT2(u2h(w0.x), vrB[0], 0.0f); hi = DOT2(u2h(w0.y), vrB[1], hi);   \
    hi = DOT2(u2h(w0.z), vrB[2], hi);   hi = DOT2(u2h(w0.w), vrB[3], hi);   \
    hi = DOT2(u2h(w1.x), vrB[4], hi);   hi = DOT2(u2h(w1.y), vrB[5], hi);   \
    hi = DOT2(u2h(w1.z), vrB[6], hi);   hi = DOT2(u2h(w1.w), vrB[7], hi);   \
    {                                                                       \
        float tlo = dpp_xor8(lo), thi = dpp_xor8(hi);                       \
        float v1 = (lane & 8) ? (hi + thi) : (lo + tlo);                    \
        v1 += __shfl_xor(v1, 16);                                           \
        v1 += __shfl_xor(v1, 32);                                           \
        if (lane < 16) cacc[PAR][lane][wave] = (_Float16)v1;                \
    }                                                                       \
    /* kq_t = K q_t, published by wave 0 */                                 \
    if (wave == 0 && lane < 16) {                                           \
        float ka = DOT2(u2h(qv0), kr[0], 0.0f);                             \
        float kb2 = DOT2(u2h(qv4), kr[4], 0.0f);                            \
        ka = DOT2(u2h(qv1), kr[1], ka);  kb2 = DOT2(u2h(qv5), kr[5], kb2);  \
        ka = DOT2(u2h(qv2), kr[2], ka);  kb2 = DOT2(u2h(qv6), kr[6], kb2);  \
        ka = DOT2(u2h(qv3), kr[3], ka);  kb2 = DOT2(u2h(qv7), kr[7], kb2);  \
        cacc[PAR][lane][8] = (_Float16)(ka + kb2);                          \
    }                                                                       \
    softbar();                                                              \
} while (0)

    // bodies t = 0..2047; (RG,RA,PAR) = (t&3, (t+1)&3, t&1)
    for (int t4 = 0; t4 < 511; ++t4) {
        BODY(0, 1, 0, 1); BODY(1, 2, 1, 1); BODY(2, 3, 0, 1); BODY(3, 0, 1, 1);
    }
    BODY(0, 1, 0, 0); BODY(1, 2, 1, 0); BODY(2, 3, 0, 0); BODY(3, 0, 1, 0);
#undef BODY

    *(float2*)(out + (long)b * Hh + h0) = make_float2(s0f, s1f);
}

// ---------------------------------------------------------------------------
extern "C" void kernel_launch(void* const* d_in, const int* in_sizes, int n_in,
                              void* d_out, int out_size, void* d_ws, size_t ws_size,
                              hipStream_t stream)
{
    const float* x  = (const float*)d_in[0];
    const float* Wa = (const float*)d_in[1];
    const float* ba = (const float*)d_in[2];
    const float* Wg = (const float*)d_in[3];
    const float* bg = (const float*)d_in[4];
    const float* Wu = (const float*)d_in[5];
    const float* bu = (const float*)d_in[6];
    const float* u  = (const float*)d_in[7];
    const float* v  = (const float*)d_in[8];
    float* out = (float*)d_out;

    char* ws = (char*)d_ws;
    unsigned short* xb   = (unsigned short*)(ws);                // 67,108,864 B
    unsigned short* Wab  = (unsigned short*)(ws + 67108864);     //  2,097,152 B
    unsigned short* Wub  = (unsigned short*)(ws + 69206016);     //  2,097,152 B
    unsigned short* abuf = (unsigned short*)(ws + 71303168);     // 67,108,864 B (bf16)
    unsigned short* ubuf = (unsigned short*)(ws + 138412032);    // 67,108,864 B (bf16)
    float*          gbuf = (float*)(ws + 205520896);             //  2,097,152 B
    // Kbuf aliases the xb region: k_K runs AFTER k_gemm has consumed xb.
    float*          Kbuf = (float*)(ws);                         //  1,024 B

    hipLaunchKernelGGL(k_convert, dim3(34816), dim3(256), 0, stream,
                       x, Wa, Wu, xb, Wab, Wub);
    hipLaunchKernelGGL(k_gemm, dim3(256, 16), dim3(256), 0, stream,
                       xb, Wab, Wub, ba, bu, abuf, ubuf);
    hipLaunchKernelGGL(k_K, dim3(1), dim3(256), 0, stream, u, v, Kbuf);
    hipLaunchKernelGGL(k_g, dim3(2048), dim3(256), 0, stream,
                       x, Wg, bg, gbuf);
    hipLaunchKernelGGL(k_scan, dim3(Bb), dim3(512), 0, stream,
                       abuf, ubuf, gbuf, u, v, Kbuf, out);
}